// Round 14
// baseline (234.987 us; speedup 1.0000x reference)
//
#include <hip/hip_runtime.h>
#include <hip/hip_bf16.h>
#include <math.h>

#define WAVE 64

// R13 (194.7 us) with ONE change: chunk_hist + rank_scatter merged into a
// single kernel by recomputing all 128 chunk-hists redundantly per block
// (16 waves x 8 chunks -> LDS), killing the global hist dependency that
// forced a separate dispatch. 4 -> 3 dispatches.
// Laws: hipMemsetAsync is the only ~6.5 TB/s filler (R2/R6/R10/R12);
// avoid sparse-grid ballot shapes (R4/R5/R8 +30us); avoid serial scans
// (R1->R9 -28us); avoid cooperative (R10 +198us); keep one-wave-per-token
// softmax parallelism (R11 +20us).

// ---------------- K1: per-token softmax + top1/top2 (unchanged) -----------
__global__ void router_softmax_top2(const float* __restrict__ x,
                                    int* __restrict__ top1,
                                    int* __restrict__ top2,
                                    float* __restrict__ w1,
                                    float* __restrict__ w2,
                                    int S) {
    const int wavesPerBlock = blockDim.x >> 6;
    const int wid  = threadIdx.x >> 6;
    const int lane = threadIdx.x & 63;
    const int s = blockIdx.x * wavesPerBlock + wid;
    if (s >= S) return;

    float v = x[(size_t)s * 64 + lane];

    // argmax with lowest-index tiebreak (matches jnp.argmax)
    float bv = v; int bi = lane;
    #pragma unroll
    for (int off = 32; off >= 1; off >>= 1) {
        float ov = __shfl_xor(bv, off, WAVE);
        int   oi = __shfl_xor(bi, off, WAVE);
        if (ov > bv || (ov == bv && oi < bi)) { bv = ov; bi = oi; }
    }
    const float m = bv;
    const int t1 = bi;

    // fp32 softmax
    float e = expf(v - m);
    float sum = e;
    #pragma unroll
    for (int off = 32; off >= 1; off >>= 1) sum += __shfl_xor(sum, off, WAVE);
    const float p = e / sum;

    // second argmax with top1 masked out
    float v2 = (lane == t1) ? -INFINITY : v;
    float bv2 = v2; int bi2 = lane;
    #pragma unroll
    for (int off = 32; off >= 1; off >>= 1) {
        float ov = __shfl_xor(bv2, off, WAVE);
        int   oi = __shfl_xor(bi2, off, WAVE);
        if (ov > bv2 || (ov == bv2 && oi < bi2)) { bv2 = ov; bi2 = oi; }
    }
    const int t2 = bi2;

    const float p1 = __shfl(p, t1, WAVE);
    const float p2 = __shfl(p, t2, WAVE);

    if (lane == 0) {
        top1[s] = t1; top2[s] = t2;
        w1[s] = p1;   w2[s] = p2;
    }
}

// ---------------- K2: hist (redundant per block) + scan + rank + scatter --
// One 1024-thread block per chunk. Phase 1: wave w rebuilds hists of chunks
// w*8..w*8+7 into LDS (proven shfl-count body; parallel across blocks, the
// redundancy buys independence from other blocks). Phase 2: wave 0 runs the
// verified R13 scan + stable-count + scatter, reading LDS instead of L2.
__global__ void __launch_bounds__(1024)
hist_rank_scatter(const int* __restrict__ top1,
                  const int* __restrict__ top2,
                  const float* __restrict__ w1,
                  const float* __restrict__ w2,
                  float* __restrict__ out,
                  int S, int CAP, int nchunks) {
    extern __shared__ int2 lh[];              // [nchunks][64] = 64 KB
    const int c    = blockIdx.x;
    const int wid  = threadIdx.x >> 6;
    const int lane = threadIdx.x & 63;

    // phase 1: build all chunk hists (16 waves x nchunks/16 chunks each)
    const int cpw = nchunks >> 4;             // 8
    for (int k = 0; k < cpw; ++k) {
        const int cc = wid * cpw + k;
        const int t1 = top1[cc * 64 + lane];
        const int t2 = top2[cc * 64 + lane];
        int c1 = 0, c2 = 0;
        #pragma unroll 8
        for (int j = 0; j < 64; ++j) {
            c1 += (__shfl(t1, j, WAVE) == lane);
            c2 += (__shfl(t2, j, WAVE) == lane);
        }
        lh[cc * 64 + lane] = make_int2(c1, c2);
    }
    __syncthreads();

    // phase 2: wave 0 only — scan + within-chunk stable ranks + scatter
    if (threadIdx.x < 64) {
        const int i = lane;
        const int s = c * 64 + i;

        // hoisted token loads (overlap with the LDS scan)
        const int t1 = top1[s];
        const int t2 = top2[s];
        const float v1 = w1[s];
        const float v2 = w2[s];

        // thread i = expert i: exclusive base + pre-drop top-1 totals
        int b1 = 0, b2 = 0, tot1 = 0;
        #pragma unroll 8
        for (int cc = 0; cc < nchunks; ++cc) {
            const int2 h = lh[cc * 64 + i];
            const int lt = (cc < c);
            b1   += lt ? h.x : 0;
            b2   += lt ? h.y : 0;
            tot1 += h.x;
        }

        // within-chunk stable counts
        int cnt1 = 0, cnt2 = 0;
        #pragma unroll 8
        for (int j = 0; j < 64; ++j) {
            const int o1 = __shfl(t1, j, WAVE);
            const int o2 = __shfl(t2, j, WAVE);
            cnt1 += (o1 == t1) && (j < i);
            cnt2 += (o2 == t2) && (j < i);
        }

        const int rank1 = __shfl(b1, t1, WAVE) + cnt1;
        const int rank2 = __shfl(b2, t2, WAVE) + cnt2 + __shfl(tot1, t2, WAVE);

        const size_t secoff = (size_t)S * 64 * CAP;
        if (rank1 < CAP) {
            const size_t idx = ((size_t)s * 64 + t1) * CAP + rank1;
            out[idx] = v1;
            out[secoff + idx] = 1.0f;
        }
        if (rank2 < CAP) {
            const size_t idx = ((size_t)s * 64 + t2) * CAP + rank2;
            out[idx] = v2;
            out[secoff + idx] = 1.0f;
        }
    }
}

extern "C" void kernel_launch(void* const* d_in, const int* in_sizes, int n_in,
                              void* d_out, int out_size, void* d_ws, size_t ws_size,
                              hipStream_t stream) {
    const float* x = (const float*)d_in[0];
    float* out = (float*)d_out;

    const int E = 64;
    const int S = in_sizes[0] / E;            // 8192
    int cap = (int)(2.0 * S / E);
    cap += cap % 2;
    if (cap < 4) cap = 4;                     // 256

    const int nchunks = S / 64;               // 128

    // workspace layout
    char* w = (char*)d_ws;
    int*   top1  = (int*)w;    w += (size_t)S * 4;
    int*   top2  = (int*)w;    w += (size_t)S * 4;
    float* w1    = (float*)w;  w += (size_t)S * 4;
    float* w2    = (float*)w;  w += (size_t)S * 4;

    // 1) zero the dense output FIRST (the roofline term; ~6.5 TB/s)
    hipMemsetAsync(d_out, 0, (size_t)out_size * sizeof(float), stream);

    // 2) softmax + top2 (one wave per token, 2048 blocks)
    {
        const int wavesPerBlock = 4;
        const int blocks = (S + wavesPerBlock - 1) / wavesPerBlock;
        router_softmax_top2<<<blocks, wavesPerBlock * 64, 0, stream>>>(
            x, top1, top2, w1, w2, S);
    }

    // 3) fused hist + scan + ranks + scatter (one 1024-thread block/chunk)
    {
        const size_t lds = (size_t)nchunks * 64 * sizeof(int2);  // 64 KB
        hist_rank_scatter<<<nchunks, 1024, lds, stream>>>(top1, top2, w1, w2,
                                                          out, S, cap, nchunks);
    }
}